// Round 1
// baseline (259.102 us; speedup 1.0000x reference)
//
#include <hip/hip_runtime.h>
#include <math.h>

// ---------------- problem constants ----------------
#define P      6400      // SAMPLE*SAMPLE patches per image
#define K      49        // PATCH*PATCH channels (C=1)
#define KP     64        // K padded to MFMA granularity (pad channels are 0)
#define FH     169       // patch-grid H = W = (512-7)/3+1
#define IMG    512
#define EPSF   2.220446049250313e-16f
#define HWT    2.0f      // H_WEIGHT
#define LOCC   0.05f     // LAMBDA_OCC

// ---------------- sweep tiling ----------------
#define CSPLIT 50
#define QCHUNK (P / CSPLIT)   // 128 columns per block; 128 rows per block
#define NSWBLK (CSPLIT * (P / 128))   // 2500 sweep blocks

typedef __attribute__((ext_vector_type(8))) short bf16x8;  // 8 bf16 = 4 VGPR
typedef __attribute__((ext_vector_type(4))) float f32x4;

__device__ inline unsigned bfbits(float x)   // f32 -> bf16 bits, RNE
{
    unsigned u = __float_as_uint(x);
    return (u + 0x7FFFu + ((u >> 16) & 1u)) >> 16;
}

// =====================================================================
// 1) k_prep: (a) init atomic/hist buffers + tickets (first 25 blocks)
//            (b) refer-patch gather -> per-(c, 256-block) partial sums
//    grid = K*P/256 = 1225 blocks; each block lies in one c slice.
//    No f32 feature round-trip anymore: normpack re-gathers directly.
// =====================================================================
__global__ void k_prep(const float* __restrict__ rf, const float* __restrict__ rfield,
                       float* __restrict__ ypart,
                       unsigned long long* __restrict__ packed1,
                       int* __restrict__ counts, unsigned* __restrict__ mbits,
                       int* __restrict__ tickets)
{
    int t = threadIdx.x;
    int gid = blockIdx.x * 256 + t;

    // ---- init section (independent buffers, consumed by later kernels)
    if (gid < P) {
        packed1[gid] = 0xFFFFFFFFFFFFFFFFULL;
        counts[gid]  = 0;
        mbits[gid]   = 0xFFFFFFFFu;
    }
    if (gid < 2) tickets[gid] = 0;

    // ---- refer channel-mean partials
    int c = gid / P;
    int p = gid - c * P;             // block fully inside one c (P % 256 == 0)
    float fx = rfield[p * 2 + 0];
    float fy = rfield[p * 2 + 1];
    float gx = fx * 2.0f - 1.0f;
    float gy = fy * 2.0f - 1.0f;
    int ix = (int)rintf(((gx + 1.0f) * (float)FH - 1.0f) * 0.5f);
    int iy = (int)rintf(((gy + 1.0f) * (float)FH - 1.0f) * 0.5f);
    ix = min(max(ix, 0), FH - 1);
    iy = min(max(iy, 0), FH - 1);
    int ky = c / 7, kx = c - ky * 7;
    float v = rf[(iy * 3 + ky) * IMG + (ix * 3 + kx)];

    // wave shuffle reduce (64 lanes), then 4 waves via LDS
    float s = v;
#pragma unroll
    for (int m = 1; m < 64; m <<= 1) s += __shfl_xor(s, m, 64);
    __shared__ float acc4[4];
    int l = t & 63, w = t >> 6;
    if (l == 0) acc4[w] = s;
    __syncthreads();
    if (t == 0) ypart[c * 25 + (p >> 8)] = acc4[0] + acc4[1] + acc4[2] + acc4[3];
}

// =====================================================================
// 2) mean-subtract + L2-normalize + pack to bf16, TRANSPOSED [p][64]
//    Gathers the 49 patch values straight from the image into registers
//    (no f32 feature staging). ym computed in-block from ypart.
// =====================================================================
__global__ void k_normpack(const float* __restrict__ tf, const float* __restrict__ rf,
                           const float* __restrict__ tfield, const float* __restrict__ rfield,
                           const float* __restrict__ ypart,
                           unsigned short* __restrict__ tb, unsigned short* __restrict__ rb)
{
    __shared__ float ym[K];
    int t = threadIdx.x;
    if (t < K) {
        float s = 0.f;
#pragma unroll
        for (int i = 0; i < 25; ++i) s += ypart[t * 25 + i];
        ym[t] = s * (1.0f / (float)P);
    }
    __syncthreads();

    int gid = blockIdx.x * 256 + t;      // grid = 2P/256 = 50 blocks
    int sel = gid >= P;
    int p = sel ? gid - P : gid;
    const float* field = sel ? rfield : tfield;
    const float* feat  = sel ? rf : tf;
    unsigned short* ob = sel ? rb : tb;

    float fx = field[p * 2 + 0];
    float fy = field[p * 2 + 1];
    float gx = fx * 2.0f - 1.0f;
    float gy = fy * 2.0f - 1.0f;
    int ix = (int)rintf(((gx + 1.0f) * (float)FH - 1.0f) * 0.5f);
    int iy = (int)rintf(((gy + 1.0f) * (float)FH - 1.0f) * 0.5f);
    ix = min(max(ix, 0), FH - 1);
    iy = min(max(iy, 0), FH - 1);
    const float* base = feat + (iy * 3) * IMG + ix * 3;

    float v[K];
#pragma unroll
    for (int ky = 0; ky < 7; ++ky)
#pragma unroll
        for (int kx = 0; kx < 7; ++kx)
            v[ky * 7 + kx] = base[ky * IMG + kx];

    float ss = 0.f;
#pragma unroll
    for (int c = 0; c < K; ++c) {
        float x = v[c] - ym[c];
        v[c] = x;
        ss += x * x;
    }
    float rn = 1.0f / (sqrtf(ss) + EPSF);

    unsigned wbuf[KP / 2];
#pragma unroll
    for (int i = 0; i < KP / 2; ++i) {
        int c0 = 2 * i, c1 = 2 * i + 1;
        float x0 = (c0 < K) ? v[c0] * rn : 0.f;
        float x1 = (c1 < K) ? v[c1] * rn : 0.f;
        wbuf[i] = (bfbits(x1) << 16) | bfbits(x0);
    }
    uint4* o = (uint4*)(ob + p * KP);    // p*128 bytes: 16B aligned
#pragma unroll
    for (int i = 0; i < KP / 8; ++i)
        o[i] = make_uint4(wbuf[4 * i], wbuf[4 * i + 1], wbuf[4 * i + 2], wbuf[4 * i + 3]);
}

// =====================================================================
// 3) MFMA sim sweeps. block = 4 waves; 128(p) x 128(q) tile; K=64 (2 steps).
//    A/B frag: lane l holds 8 contiguous k at row l&15, k0=(l>>4)*8
//    C/D:      col=l&15, row=(l>>4)*4+reg
//    MODE 1: per-row argmin of d0 (first-occurrence ties) -> atomicMin u64
//            + last-finishing block builds the histogram (fused k_hist)
//    MODE 2: per-row min of d0 + cnt[q]*LOCC              -> atomicMin u32
//    MODE 3: per-row sum exp((1 - d/(m+EPS))*H)           -> Spart
// =====================================================================
template<int MODE>
__global__ __launch_bounds__(256, 4)
void k_sweep(const unsigned short* __restrict__ tb, const unsigned short* __restrict__ rb,
             int* __restrict__ counts, const unsigned* __restrict__ mbits_in,
             unsigned long long* __restrict__ packed1, unsigned* __restrict__ mbits_out,
             float* __restrict__ Spart, int* __restrict__ ticket)
{
    const int p0 = blockIdx.x * 128, q0 = blockIdx.y * QCHUNK;
    const int t  = threadIdx.x;
    const int w  = t >> 6, l = t & 63;
    const int l15 = l & 15, lg = l >> 4;

    bf16x8 afr[2][2];
#pragma unroll
    for (int mt = 0; mt < 2; ++mt)
#pragma unroll
        for (int ks = 0; ks < 2; ++ks)
            afr[mt][ks] = *(const bf16x8*)(tb + (p0 + w * 32 + mt * 16 + l15) * KP + ks * 32 + lg * 8);

    f32x4 acc[2][8];
#pragma unroll
    for (int mt = 0; mt < 2; ++mt)
#pragma unroll
        for (int qt = 0; qt < 8; ++qt) acc[mt][qt] = (f32x4){0.f, 0.f, 0.f, 0.f};

#pragma unroll
    for (int qt = 0; qt < 8; ++qt) {
        bf16x8 b0 = *(const bf16x8*)(rb + (q0 + qt * 16 + l15) * KP + 0  + lg * 8);
        bf16x8 b1 = *(const bf16x8*)(rb + (q0 + qt * 16 + l15) * KP + 32 + lg * 8);
#pragma unroll
        for (int mt = 0; mt < 2; ++mt) {
            acc[mt][qt] = __builtin_amdgcn_mfma_f32_16x16x32_bf16(afr[mt][0], b0, acc[mt][qt], 0, 0, 0);
            acc[mt][qt] = __builtin_amdgcn_mfma_f32_16x16x32_bf16(afr[mt][1], b1, acc[mt][qt], 0, 0, 0);
        }
    }

    float osv[8];
    if (MODE >= 2) {
#pragma unroll
        for (int qt = 0; qt < 8; ++qt) osv[qt] = (float)counts[q0 + qt * 16 + l15] * LOCC;
    }

#pragma unroll
    for (int mt = 0; mt < 2; ++mt) {
#pragma unroll
        for (int r = 0; r < 4; ++r) {
            int p = p0 + w * 32 + mt * 16 + lg * 4 + r;
            float rinv = 0.f;
            if (MODE == 3) rinv = 1.0f / (__uint_as_float(mbits_in[p]) + EPSF);

            float bv = 1e30f; int bi = 0; float s = 0.f;
#pragma unroll
            for (int qt = 0; qt < 8; ++qt) {    // qt ascending -> q ascending per lane
                float d = fmaxf((1.0f - acc[mt][qt][r]) * 0.5f, 0.0f);
                if (MODE >= 2) d += osv[qt];
                if (MODE == 1) {
                    bool upd = d < bv;          // strict <: first occurrence wins
                    bi = upd ? (q0 + qt * 16 + l15) : bi;
                    bv = upd ? d : bv;
                } else if (MODE == 2) {
                    bv = fminf(bv, d);
                } else {
                    s += __expf((1.0f - d * rinv) * HWT);
                }
            }

            // reduce across the 16 lanes of this row group (masks 1,2,4,8)
            if (MODE == 1) {
                // packed (value,index) lexicographic min: d >= 0 so f32 bits
                // are order-preserving; ties -> smaller q. Same semantics as
                // (ov<bv)||(ov==bv&&oi<bi) but ~half the VALU ops.
                unsigned long long enc =
                    ((unsigned long long)__float_as_uint(bv) << 32) | (unsigned)bi;
#pragma unroll
                for (int m = 1; m < 16; m <<= 1) {
                    unsigned long long o = __shfl_xor(enc, m, 64);
                    enc = (o < enc) ? o : enc;
                }
                if (l15 == 0) atomicMin(&packed1[p], enc);
            } else if (MODE == 2) {
#pragma unroll
                for (int m = 1; m < 16; m <<= 1) bv = fminf(bv, __shfl_xor(bv, m, 64));
                if (l15 == 0) atomicMin(&mbits_out[p], __float_as_uint(bv));
            } else {
#pragma unroll
                for (int m = 1; m < 16; m <<= 1) s += __shfl_xor(s, m, 64);
                if (l15 == 0) Spart[blockIdx.y * P + p] = s;
            }
        }
    }

    // ---- fused histogram: last block to finish replays packed1 -> counts
    if (MODE == 1) {
        __syncthreads();                 // all atomicMins issued + drained (vmcnt 0 at barrier)
        __threadfence();                 // device-scope release
        __shared__ int lastblk;
        if (t == 0) lastblk = (atomicAdd(ticket, 1) == NSWBLK - 1);
        __syncthreads();
        if (lastblk) {
            for (int p = t; p < P; p += 256) {
                // atomic read-modify-write with 0: device-scope read of the final min
                unsigned long long v = atomicAdd(&packed1[p], 0ULL);
                atomicAdd(&counts[(unsigned)(v & 0xffffffffULL)], 1);
            }
        }
    }
}

// =====================================================================
// 4) epilogue: per-row -log(CX), block partials, last block finishes
//    (deterministic: last block sums the 50 partials in index order)
// =====================================================================
__global__ void k_loss(const float* __restrict__ Spart, const unsigned* __restrict__ mbits,
                       float* __restrict__ partial, int* __restrict__ ticket,
                       float* __restrict__ out)
{
    int b = blockIdx.x, t = threadIdx.x;   // 50 blocks x 128 threads
    int p = b * 128 + t;
    float s = 0.f;
#pragma unroll
    for (int cb = 0; cb < CSPLIT; ++cb) s += Spart[cb * P + p];
    float m = __uint_as_float(mbits[p]);
    float lw = (1.0f - m / (m + EPSF)) * HWT;   // log of max weight
    float v = logf(s) - lw;                      // -log(CX)
    __shared__ float red[128];
    red[t] = v; __syncthreads();
    for (int w = 64; w > 0; w >>= 1) { if (t < w) red[t] += red[t + w]; __syncthreads(); }

    __shared__ int lastblk;
    if (t == 0) {
        atomicExch(&partial[b], red[0]);   // device-scope write (safe across XCD L2s)
        __threadfence();
        lastblk = (atomicAdd(ticket, 1) == CSPLIT - 1);
    }
    __syncthreads();
    if (lastblk && t < 64) {
        float x = (t < CSPLIT) ? atomicAdd(&partial[t], 0.0f) : 0.f;  // atomic read
#pragma unroll
        for (int mm = 32; mm > 0; mm >>= 1) x += __shfl_down(x, mm, 64);
        if (t == 0) out[0] = x * (1.0f / (float)P);
    }
}

// =====================================================================
extern "C" void kernel_launch(void* const* d_in, const int* in_sizes, int n_in,
                              void* d_out, int out_size, void* d_ws, size_t ws_size,
                              hipStream_t stream)
{
    const float* tf  = (const float*)d_in[0];
    const float* rf  = (const float*)d_in[1];
    const float* tfd = (const float*)d_in[2];
    const float* rfd = (const float*)d_in[3];
    float* out = (float*)d_out;

    float* ws = (float*)d_ws;
    float* ypart = ws;                                       // K*25 = 1225 f
    unsigned short* tb = (unsigned short*)(ws + 2048);       // P*KP bf16 = 204800 f
    unsigned short* rb = (unsigned short*)(ws + 206848);     // P*KP bf16 = 204800 f
    float* Spart = ws + 411648;                              // CSPLIT*P = 320000 f
    unsigned long long* packed1 = (unsigned long long*)(ws + 731648); // P u64 = 12800 f
    int*      counts  = (int*)(ws + 744448);                 // P
    unsigned* mbits   = (unsigned*)(ws + 750848);            // P
    float*    partial = ws + 757248;                         // 64
    int*      tickets = (int*)(ws + 757312);                 // 2
    // total ~757314 floats ~= 3.0 MB

    // 6 kernels (was 9): init+ymean | normpack | sweep1+hist | sweep2 | sweep3 | loss+final
    k_prep<<<K * P / 256, 256, 0, stream>>>(rf, rfd, ypart, packed1, counts, mbits, tickets);
    k_normpack<<<2 * P / 256, 256, 0, stream>>>(tf, rf, tfd, rfd, ypart, tb, rb);

    dim3 g(P / 128, CSPLIT);
    k_sweep<1><<<g, 256, 0, stream>>>(tb, rb, counts, nullptr, packed1, nullptr, nullptr, &tickets[0]);
    k_sweep<2><<<g, 256, 0, stream>>>(tb, rb, counts, nullptr, nullptr, mbits, nullptr, nullptr);
    k_sweep<3><<<g, 256, 0, stream>>>(tb, rb, counts, mbits, nullptr, nullptr, Spart, nullptr);

    k_loss<<<CSPLIT, 128, 0, stream>>>(Spart, mbits, partial, &tickets[1], out);
}

// Round 2
// 69.191 us; speedup vs baseline: 3.7448x; 3.7448x over previous
//
#include <hip/hip_runtime.h>
#include <math.h>

// ---------------- problem constants ----------------
#define P      6400      // SAMPLE*SAMPLE patches per image
#define K      49        // PATCH*PATCH channels (C=1)
#define KP     64        // K padded to MFMA granularity (pad channels are 0)
#define FH     169       // patch-grid H = W = (512-7)/3+1
#define IMG    512
#define EPSF   2.220446049250313e-16f
#define HWT    2.0f      // H_WEIGHT
#define LOCC   0.05f     // LAMBDA_OCC

// ---------------- sweep tiling ----------------
#define CSPLIT 50
#define QCHUNK (P / CSPLIT)   // 128 columns per block; 128 rows per block

typedef __attribute__((ext_vector_type(8))) short bf16x8;  // 8 bf16 = 4 VGPR
typedef __attribute__((ext_vector_type(4))) float f32x4;

__device__ inline unsigned bfbits(float x)   // f32 -> bf16 bits, RNE
{
    unsigned u = __float_as_uint(x);
    return (u + 0x7FFFu + ((u >> 16) & 1u)) >> 16;
}

// =====================================================================
// 1) k_prep: (a) init atomic/hist buffers + tickets
//            (b) refer-patch gather -> per-(c, 256-block) partial sums
//    grid = K*P/256 = 1225 blocks; each block lies in one c slice.
// =====================================================================
__global__ void k_prep(const float* __restrict__ rf, const float* __restrict__ rfield,
                       float* __restrict__ ypart,
                       unsigned long long* __restrict__ packed1,
                       int* __restrict__ counts, unsigned* __restrict__ mbits,
                       int* __restrict__ tickets)
{
    int t = threadIdx.x;
    int gid = blockIdx.x * 256 + t;

    // ---- init section (independent buffers, consumed by later kernels)
    if (gid < P) {
        packed1[gid] = 0xFFFFFFFFFFFFFFFFULL;
        counts[gid]  = 0;
        mbits[gid]   = 0xFFFFFFFFu;
    }
    if (gid < 2) tickets[gid] = 0;

    // ---- refer channel-mean partials
    int c = gid / P;
    int p = gid - c * P;             // block fully inside one c (P % 256 == 0)
    float fx = rfield[p * 2 + 0];
    float fy = rfield[p * 2 + 1];
    float gx = fx * 2.0f - 1.0f;
    float gy = fy * 2.0f - 1.0f;
    int ix = (int)rintf(((gx + 1.0f) * (float)FH - 1.0f) * 0.5f);
    int iy = (int)rintf(((gy + 1.0f) * (float)FH - 1.0f) * 0.5f);
    ix = min(max(ix, 0), FH - 1);
    iy = min(max(iy, 0), FH - 1);
    int ky = c / 7, kx = c - ky * 7;
    float v = rf[(iy * 3 + ky) * IMG + (ix * 3 + kx)];

    // wave shuffle reduce (64 lanes), then 4 waves via LDS
    float s = v;
#pragma unroll
    for (int m = 1; m < 64; m <<= 1) s += __shfl_xor(s, m, 64);
    __shared__ float acc4[4];
    int l = t & 63, w = t >> 6;
    if (l == 0) acc4[w] = s;
    __syncthreads();
    if (t == 0) ypart[c * 25 + (p >> 8)] = acc4[0] + acc4[1] + acc4[2] + acc4[3];
}

// =====================================================================
// 2) mean-subtract + L2-normalize + pack to bf16, TRANSPOSED [p][64]
//    Gathers the 49 patch values straight from the image into registers.
// =====================================================================
__global__ void k_normpack(const float* __restrict__ tf, const float* __restrict__ rf,
                           const float* __restrict__ tfield, const float* __restrict__ rfield,
                           const float* __restrict__ ypart,
                           unsigned short* __restrict__ tb, unsigned short* __restrict__ rb)
{
    __shared__ float ym[K];
    int t = threadIdx.x;
    if (t < K) {
        float s = 0.f;
#pragma unroll
        for (int i = 0; i < 25; ++i) s += ypart[t * 25 + i];
        ym[t] = s * (1.0f / (float)P);
    }
    __syncthreads();

    int gid = blockIdx.x * 256 + t;      // grid = 2P/256 = 50 blocks
    int sel = gid >= P;
    int p = sel ? gid - P : gid;
    const float* field = sel ? rfield : tfield;
    const float* feat  = sel ? rf : tf;
    unsigned short* ob = sel ? rb : tb;

    float fx = field[p * 2 + 0];
    float fy = field[p * 2 + 1];
    float gx = fx * 2.0f - 1.0f;
    float gy = fy * 2.0f - 1.0f;
    int ix = (int)rintf(((gx + 1.0f) * (float)FH - 1.0f) * 0.5f);
    int iy = (int)rintf(((gy + 1.0f) * (float)FH - 1.0f) * 0.5f);
    ix = min(max(ix, 0), FH - 1);
    iy = min(max(iy, 0), FH - 1);
    const float* base = feat + (iy * 3) * IMG + ix * 3;

    float v[K];
#pragma unroll
    for (int ky = 0; ky < 7; ++ky)
#pragma unroll
        for (int kx = 0; kx < 7; ++kx)
            v[ky * 7 + kx] = base[ky * IMG + kx];

    float ss = 0.f;
#pragma unroll
    for (int c = 0; c < K; ++c) {
        float x = v[c] - ym[c];
        v[c] = x;
        ss += x * x;
    }
    float rn = 1.0f / (sqrtf(ss) + EPSF);

    unsigned wbuf[KP / 2];
#pragma unroll
    for (int i = 0; i < KP / 2; ++i) {
        int c0 = 2 * i, c1 = 2 * i + 1;
        float x0 = (c0 < K) ? v[c0] * rn : 0.f;
        float x1 = (c1 < K) ? v[c1] * rn : 0.f;
        wbuf[i] = (bfbits(x1) << 16) | bfbits(x0);
    }
    uint4* o = (uint4*)(ob + p * KP);    // p*128 bytes: 16B aligned
#pragma unroll
    for (int i = 0; i < KP / 8; ++i)
        o[i] = make_uint4(wbuf[4 * i], wbuf[4 * i + 1], wbuf[4 * i + 2], wbuf[4 * i + 3]);
}

// =====================================================================
// 3) MFMA sim sweeps. block = 4 waves; 128(p) x 128(q) tile; K=64 (2 steps).
//    B tile (shared by all 4 waves) staged once in LDS, XOR-swizzled in
//    16B chunks: lds_chunk(r, c^(r&7)) = glb_chunk(r, c). Read side uses
//    the same involution -> 8 distinct bank-quads per wave access
//    (the ds_read_b128 minimum; conflict-free).
//    A/B frag: lane l holds 8 contiguous k at row l&15, k0=(l>>4)*8
//    C/D:      col=l&15, row=(l>>4)*4+reg
//    MODE 1: per-row argmin of d0 (first-occurrence ties) -> atomicMin u64
//    MODE 2: per-row min of d0 + cnt[q]*LOCC              -> atomicMin u32
//    MODE 3: per-row sum exp((1 - d/(m+EPS))*H)           -> Spart
// =====================================================================
template<int MODE>
__global__ __launch_bounds__(256, 4)
void k_sweep(const unsigned short* __restrict__ tb, const unsigned short* __restrict__ rb,
             const int* __restrict__ counts, const unsigned* __restrict__ mbits_in,
             unsigned long long* __restrict__ packed1, unsigned* __restrict__ mbits_out,
             float* __restrict__ Spart)
{
    __shared__ uint4 bs[1024];           // 16 KB: 128 rows x 8 chunks of 16B
    const int p0 = blockIdx.x * 128, q0 = blockIdx.y * QCHUNK;
    const int t  = threadIdx.x;
    const int w  = t >> 6, l = t & 63;
    const int l15 = l & 15, lg = l >> 4;

    // A fragments: issue global loads first so they overlap the staging
    bf16x8 afr[2][2];
#pragma unroll
    for (int mt = 0; mt < 2; ++mt)
#pragma unroll
        for (int ks = 0; ks < 2; ++ks)
            afr[mt][ks] = *(const bf16x8*)(tb + (p0 + w * 32 + mt * 16 + l15) * KP + ks * 32 + lg * 8);

    // ---- stage B tile: 1024 16B chunks; 4 per thread, XOR-swizzled write
    {
        const int r = t >> 1;            // 2 threads per row, 4 chunks each
        const int cbase = (t & 1) * 4;
        const uint4* src = (const uint4*)(rb + (q0 + r) * KP);
#pragma unroll
        for (int i = 0; i < 4; ++i) {
            int c = cbase + i;
            bs[r * 8 + (c ^ (r & 7))] = src[c];
        }
    }
    __syncthreads();

    f32x4 acc[2][8];
#pragma unroll
    for (int mt = 0; mt < 2; ++mt)
#pragma unroll
        for (int qt = 0; qt < 8; ++qt) acc[mt][qt] = (f32x4){0.f, 0.f, 0.f, 0.f};

#pragma unroll
    for (int qt = 0; qt < 8; ++qt) {
        const int row = qt * 16 + l15;
        bf16x8 b0 = *(const bf16x8*)&bs[row * 8 + ((0 + lg) ^ (row & 7))];
        bf16x8 b1 = *(const bf16x8*)&bs[row * 8 + ((4 + lg) ^ (row & 7))];
#pragma unroll
        for (int mt = 0; mt < 2; ++mt) {
            acc[mt][qt] = __builtin_amdgcn_mfma_f32_16x16x32_bf16(afr[mt][0], b0, acc[mt][qt], 0, 0, 0);
            acc[mt][qt] = __builtin_amdgcn_mfma_f32_16x16x32_bf16(afr[mt][1], b1, acc[mt][qt], 0, 0, 0);
        }
    }

    float osv[8];
    if (MODE >= 2) {
#pragma unroll
        for (int qt = 0; qt < 8; ++qt) osv[qt] = (float)counts[q0 + qt * 16 + l15] * LOCC;
    }

#pragma unroll
    for (int mt = 0; mt < 2; ++mt) {
#pragma unroll
        for (int r = 0; r < 4; ++r) {
            int p = p0 + w * 32 + mt * 16 + lg * 4 + r;
            float rinv = 0.f;
            if (MODE == 3) rinv = 1.0f / (__uint_as_float(mbits_in[p]) + EPSF);

            float bv = 1e30f; int bi = 0; float s = 0.f;
#pragma unroll
            for (int qt = 0; qt < 8; ++qt) {    // qt ascending -> q ascending per lane
                float d = fmaxf((1.0f - acc[mt][qt][r]) * 0.5f, 0.0f);
                if (MODE >= 2) d += osv[qt];
                if (MODE == 1) {
                    bool upd = d < bv;          // strict <: first occurrence wins
                    bi = upd ? (q0 + qt * 16 + l15) : bi;
                    bv = upd ? d : bv;
                } else if (MODE == 2) {
                    bv = fminf(bv, d);
                } else {
                    s += __expf((1.0f - d * rinv) * HWT);
                }
            }

            // reduce across the 16 lanes of this row group (masks 1,2,4,8)
            if (MODE == 1) {
                // packed (value,index) lexicographic min: d >= 0 so f32 bits
                // are order-preserving; ties -> smaller q.
                unsigned long long enc =
                    ((unsigned long long)__float_as_uint(bv) << 32) | (unsigned)bi;
#pragma unroll
                for (int m = 1; m < 16; m <<= 1) {
                    unsigned long long o = __shfl_xor(enc, m, 64);
                    enc = (o < enc) ? o : enc;
                }
                if (l15 == 0) atomicMin(&packed1[p], enc);
            } else if (MODE == 2) {
#pragma unroll
                for (int m = 1; m < 16; m <<= 1) bv = fminf(bv, __shfl_xor(bv, m, 64));
                if (l15 == 0) atomicMin(&mbits_out[p], __float_as_uint(bv));
            } else {
#pragma unroll
                for (int m = 1; m < 16; m <<= 1) s += __shfl_xor(s, m, 64);
                if (l15 == 0) Spart[blockIdx.y * P + p] = s;
            }
        }
    }
}

// =====================================================================
// 4) histogram (separate kernel: kernel boundary provides the global
//    ordering; fusing this cost 170us in R1 via per-wave threadfences)
// =====================================================================
__global__ void k_hist(const unsigned long long* __restrict__ packed1,
                       int* __restrict__ counts)
{
    int p = blockIdx.x * blockDim.x + threadIdx.x;
    if (p < P) atomicAdd(&counts[(unsigned)(packed1[p] & 0xffffffffULL)], 1);
}

// =====================================================================
// 5) epilogue: per-row -log(CX), block partials, last block finishes
//    (deterministic: last block sums the 50 partials in index order;
//    fence is single-thread x 50 blocks -> noise)
// =====================================================================
__global__ void k_loss(const float* __restrict__ Spart, const unsigned* __restrict__ mbits,
                       float* __restrict__ partial, int* __restrict__ ticket,
                       float* __restrict__ out)
{
    int b = blockIdx.x, t = threadIdx.x;   // 50 blocks x 128 threads
    int p = b * 128 + t;
    float s = 0.f;
#pragma unroll
    for (int cb = 0; cb < CSPLIT; ++cb) s += Spart[cb * P + p];
    float m = __uint_as_float(mbits[p]);
    float lw = (1.0f - m / (m + EPSF)) * HWT;   // log of max weight
    float v = logf(s) - lw;                      // -log(CX)
    __shared__ float red[128];
    red[t] = v; __syncthreads();
    for (int w = 64; w > 0; w >>= 1) { if (t < w) red[t] += red[t + w]; __syncthreads(); }

    __shared__ int lastblk;
    if (t == 0) {
        atomicExch(&partial[b], red[0]);   // device-scope write (coherent point)
        __threadfence();
        lastblk = (atomicAdd(ticket, 1) == CSPLIT - 1);
    }
    __syncthreads();
    if (lastblk && t < 64) {
        float x = (t < CSPLIT) ? atomicAdd(&partial[t], 0.0f) : 0.f;  // atomic read
#pragma unroll
        for (int mm = 32; mm > 0; mm >>= 1) x += __shfl_down(x, mm, 64);
        if (t == 0) out[0] = x * (1.0f / (float)P);
    }
}

// =====================================================================
extern "C" void kernel_launch(void* const* d_in, const int* in_sizes, int n_in,
                              void* d_out, int out_size, void* d_ws, size_t ws_size,
                              hipStream_t stream)
{
    const float* tf  = (const float*)d_in[0];
    const float* rf  = (const float*)d_in[1];
    const float* tfd = (const float*)d_in[2];
    const float* rfd = (const float*)d_in[3];
    float* out = (float*)d_out;

    float* ws = (float*)d_ws;
    float* ypart = ws;                                       // K*25 = 1225 f
    unsigned short* tb = (unsigned short*)(ws + 2048);       // P*KP bf16 = 204800 f
    unsigned short* rb = (unsigned short*)(ws + 206848);     // P*KP bf16 = 204800 f
    float* Spart = ws + 411648;                              // CSPLIT*P = 320000 f
    unsigned long long* packed1 = (unsigned long long*)(ws + 731648); // P u64 = 12800 f
    int*      counts  = (int*)(ws + 744448);                 // P
    unsigned* mbits   = (unsigned*)(ws + 750848);            // P
    float*    partial = ws + 757248;                         // 64
    int*      tickets = (int*)(ws + 757312);                 // 2
    // total ~757314 floats ~= 3.0 MB

    // 7 kernels: prep | normpack | sweep1 | hist | sweep2 | sweep3 | loss+final
    k_prep<<<K * P / 256, 256, 0, stream>>>(rf, rfd, ypart, packed1, counts, mbits, tickets);
    k_normpack<<<2 * P / 256, 256, 0, stream>>>(tf, rf, tfd, rfd, ypart, tb, rb);

    dim3 g(P / 128, CSPLIT);
    k_sweep<1><<<g, 256, 0, stream>>>(tb, rb, nullptr, nullptr, packed1, nullptr, nullptr);
    k_hist<<<(P + 255) / 256, 256, 0, stream>>>(packed1, counts);
    k_sweep<2><<<g, 256, 0, stream>>>(tb, rb, counts, nullptr, nullptr, mbits, nullptr);
    k_sweep<3><<<g, 256, 0, stream>>>(tb, rb, counts, mbits, nullptr, nullptr, Spart);

    k_loss<<<CSPLIT, 128, 0, stream>>>(Spart, mbits, partial, &tickets[1], out);
}